// Round 16
// baseline (241.251 us; speedup 1.0000x reference)
//
#include <hip/hip_runtime.h>
#include <hip/hip_bf16.h>

typedef _Float16 f16x8 __attribute__((ext_vector_type(8)));
typedef unsigned short u16x8 __attribute__((ext_vector_type(8)));
typedef unsigned short u16x4 __attribute__((ext_vector_type(4)));
typedef float f32x4 __attribute__((ext_vector_type(4)));

static constexpr int Bn = 2;
static constexpr int Tn = 2048;
static constexpr int En = 1024;
static constexpr int Hn = 16;
static constexpr int Dn = 64;
#define LOG2E 1.44269504088896340736f

static constexpr int TS = 136;  // qkv epilogue transpose stride
static constexpr int PS = 40;   // attn P-chunk row stride (shorts)

__device__ __forceinline__ unsigned short f2h(float x) {
  _Float16 h = (_Float16)x;
  return __builtin_bit_cast(unsigned short, h);
}
__device__ __forceinline__ float h2f(unsigned short u) {
  return (float)__builtin_bit_cast(_Float16, u);
}
__device__ __forceinline__ f16x8 ldh8(const unsigned short* p) {
  return __builtin_bit_cast(f16x8, *reinterpret_cast<const u16x8*>(p));
}
__device__ __forceinline__ unsigned int pk2(float a, float b) {
  return __builtin_bit_cast(unsigned int, __builtin_amdgcn_cvt_pkrtz(a, b));
}
// raw v_exp_f32 (2^x, one VALU inst); args <= 0, flush-to-zero is wanted
__device__ __forceinline__ float fexp2(float x) {
  return __builtin_amdgcn_exp2f(x);
}
// async global->LDS, 16B/lane; LDS dest must be wave-uniform base (+lane*16)
__device__ __forceinline__ void gld16(const void* g, void* l) {
  __builtin_amdgcn_global_load_lds(
      (__attribute__((address_space(1))) void*)(const_cast<void*>(g)),
      (__attribute__((address_space(3))) void*)(l), 16, 0, 0);
}

// fp16 hi/lo split: (hi + lo) == x to ~22 mantissa bits
__global__ __launch_bounds__(256) void split_f32_f16(
    const float* __restrict__ src, unsigned short* __restrict__ hi,
    unsigned short* __restrict__ lo)
{
  const int i = (blockIdx.x * 256 + threadIdx.x) * 4;
  const float4 v = *reinterpret_cast<const float4*>(src + i);
  ushort4 h, l;
  h.x = f2h(v.x); l.x = f2h(v.x - h2f(h.x));
  h.y = f2h(v.y); l.y = f2h(v.y - h2f(h.y));
  h.z = f2h(v.z); l.z = f2h(v.z - h2f(h.z));
  h.w = f2h(v.w); l.w = f2h(v.w - h2f(h.w));
  *reinterpret_cast<ushort4*>(hi + i) = h;
  *reinterpret_cast<ushort4*>(lo + i) = l;
}

__global__ __launch_bounds__(256) void cvt_f32_f16(
    const float* __restrict__ src, unsigned short* __restrict__ dst)
{
  const int i = (blockIdx.x * 256 + threadIdx.x) * 4;
  const float4 v = *reinterpret_cast<const float4*>(src + i);
  ushort4 u;
  u.x = f2h(v.x); u.y = f2h(v.y); u.z = f2h(v.z); u.w = f2h(v.w);
  *reinterpret_cast<ushort4*>(dst + i) = u;
}

// QKV GEMM, fp16 (dbuf + slot-swizzle). THIS ROUND: K-loop 2x-unrolled so the
// buffer index is COMPILE-TIME (phase A: compute buf0, stage buf1; phase B:
// compute buf1, stage buf0). All LDS bases fold to constants and staged-offset
// adds become immediates — targets the 43% VALUBusy (per-iter addr recompute).
__global__ __launch_bounds__(256) void gemm_qkv(
    const unsigned short* __restrict__ xh, const unsigned short* __restrict__ xl,
    const unsigned short* __restrict__ wf,
    unsigned short* __restrict__ Qf, unsigned short* __restrict__ Kf,
    unsigned short* __restrict__ Vf, int M, int K)
{
  // 2 x (Ah 4096 | Al 4096 | B 4096 shorts) = 49152 B; epilogue reuses [0..17408)
  __shared__ unsigned short smem[2 * 12288];

  const int tid = threadIdx.x;
  const int w = tid >> 6, L = tid & 63, qd = L >> 4, lr = L & 15;
  const int m0 = blockIdx.y * 128;
  const int kk = blockIdx.x >> 3;          // 0=Q 1=K 2=V (uniform per block)
  const int hh0 = (blockIdx.x & 7) * 2;    // two heads per block
  const int wm = (w >> 1) * 64, wn = (w & 1) * 64;

  size_t aoffs[2], boffs[2];
  int lbase[2];
#pragma unroll
  for (int p = 0; p < 2; ++p) {
    const int c = p * 256 + tid;
    const int row = c >> 2, slot = c & 3;
    const int dd = row & 63, hl = row >> 6;
    const int sg = slot ^ ((row >> 1) & 3);  // swizzled global 16B slot
    aoffs[p] = (size_t)(m0 + row) * K + sg * 8;
    boffs[p] = (size_t)(dd * 48 + kk * 16 + hh0 + hl) * K + sg * 8;
    lbase[p] = (p * 4 + w) * 512;  // wave-uniform LDS base (shorts)
  }

  f32x4 acc[4][4] = {};

  // read-side swizzle: per-thread const, key = (lr>>1)&3
  const int sw = (qd ^ ((lr >> 1) & 3)) * 8;

  // stage macro-free helpers via lambdas (compile-time BUF)
  auto stage = [&](int k0s, int bufbase) {
#pragma unroll
    for (int p = 0; p < 2; ++p) {
      gld16(xh + aoffs[p] + k0s, &smem[bufbase + lbase[p]]);
      gld16(wf + boffs[p] + k0s, &smem[bufbase + 8192 + lbase[p]]);
      if (kk < 2) gld16(xl + aoffs[p] + k0s, &smem[bufbase + 4096 + lbase[p]]);
    }
  };
  auto compute = [&](int cb) {
    f16x8 afh[4], bf[4];
#pragma unroll
    for (int mt = 0; mt < 4; ++mt)
      afh[mt] = ldh8(&smem[cb + (wm + mt * 16 + lr) * 32 + sw]);
#pragma unroll
    for (int nt = 0; nt < 4; ++nt)
      bf[nt] = ldh8(&smem[cb + 8192 + (wn + nt * 16 + lr) * 32 + sw]);
    if (kk < 2) {
      f16x8 afl[4];
#pragma unroll
      for (int mt = 0; mt < 4; ++mt)
        afl[mt] = ldh8(&smem[cb + 4096 + (wm + mt * 16 + lr) * 32 + sw]);
#pragma unroll
      for (int mt = 0; mt < 4; ++mt)
#pragma unroll
        for (int nt = 0; nt < 4; ++nt) {
          acc[mt][nt] = __builtin_amdgcn_mfma_f32_16x16x32_f16(afh[mt], bf[nt], acc[mt][nt], 0, 0, 0);
          acc[mt][nt] = __builtin_amdgcn_mfma_f32_16x16x32_f16(afl[mt], bf[nt], acc[mt][nt], 0, 0, 0);
        }
    } else {
#pragma unroll
      for (int mt = 0; mt < 4; ++mt)
#pragma unroll
        for (int nt = 0; nt < 4; ++nt)
          acc[mt][nt] = __builtin_amdgcn_mfma_f32_16x16x32_f16(afh[mt], bf[nt], acc[mt][nt], 0, 0, 0);
    }
  };

  // prologue: stage tile 0 into buf 0
  stage(0, 0);
  __syncthreads();

  for (int k0 = 0; k0 < K; k0 += 64) {
    // phase A: compute buf0, stage k0+32 into buf1
    if (k0 + 32 < K) stage(k0 + 32, 12288);
    compute(0);
    __syncthreads();
    // phase B: compute buf1, stage k0+64 into buf0
    if (k0 + 64 < K) stage(k0 + 64, 0);
    compute(12288);
    __syncthreads();
  }

  // epilogue: fp16 into LDS transpose buffer -> coalesced 16B stores
  const int b = m0 >> 11;
  const int t0 = m0 & (Tn - 1);
  const float qscale = (kk == 0) ? 8.0f * LOG2E : 1.0f;
#pragma unroll
  for (int mt = 0; mt < 4; ++mt)
#pragma unroll
    for (int nt = 0; nt < 4; ++nt)
#pragma unroll
      for (int r = 0; r < 4; ++r) {
        const int ml = wm + mt * 16 + qd * 4 + r;  // C/D row=(lane>>4)*4+reg
        const int cl = wn + nt * 16 + lr;          // C/D col=lane&15
        smem[ml * TS + cl] = f2h(acc[mt][nt][r] * qscale);
      }
  __syncthreads();

  unsigned short* dst = (kk == 0) ? Qf : (kk == 1) ? Kf : Vf;
  if (kk < 2) {
#pragma unroll
    for (int p = 0; p < 8; ++p) {
      const int s = p * 256 + tid;
      const int tl = s >> 4, sub = s & 15;
      const int hl = sub >> 3, oct = sub & 7;
      const u16x8 v = *reinterpret_cast<const u16x8*>(&smem[tl * TS + hl * 64 + oct * 8]);
      *reinterpret_cast<u16x8*>(
          dst + ((size_t)(b * Hn + hh0 + hl) * Tn + t0 + tl) * Dn + oct * 8) = v;
    }
  } else {
#pragma unroll
    for (int p = 0; p < 8; ++p) {
      const int s = p * 256 + tid;
      const int cl = s >> 4, oct = s & 15;
      const int hl = cl >> 6, dd = cl & 63;
      u16x8 v;
#pragma unroll
      for (int j = 0; j < 8; ++j) v[j] = smem[(oct * 8 + j) * TS + cl];
      *reinterpret_cast<u16x8*>(
          dst + ((size_t)((b * Hn + hh0 + hl) * Dn + dd)) * Tn + t0 + oct * 8) = v;
    }
  }
}

// Flash attention (r15 measured-good, unchanged): LDS-staged K/V with XOR
// slot-swizzle, swapped-operand QK^T, log2-domain softmax with raw v_exp,
// chunked packed P, O^T epilogue.
// Qf(x8*log2e),Kf: [b,h,t,d]  Vf: [b,h,d,t]  AO: fp16.
__global__ __launch_bounds__(256, 2) void attn_kernel(
    const unsigned short* __restrict__ Qf, const unsigned short* __restrict__ Kf,
    const unsigned short* __restrict__ Vf, unsigned short* __restrict__ AOf)
{
  __shared__ unsigned short shK[2 * 128 * 32];  // [kc][j row][32]  16 KB
  __shared__ unsigned short shV[4 * 64 * 32];   // [kcv][dd][32]    16 KB
  __shared__ unsigned short shP[4 * 16 * PS];   // per-wave 16x32 chunk, 5 KB
  const int tid = threadIdx.x;
  const int w = tid >> 6, L = tid & 63, qd = L >> 4, lr = L & 15;
  const int q0 = blockIdx.x * 64;
  const int bh = blockIdx.y;
  unsigned short* myP = &shP[w * 16 * PS];

  f16x8 aq[2];
  {
    const size_t qoff = ((size_t)bh * Tn + q0 + w * 16 + lr) * Dn;
    aq[0] = ldh8(Qf + qoff + qd * 8);
    aq[1] = ldh8(Qf + qoff + 32 + qd * 8);
  }
  f16x8 ones;
#pragma unroll
  for (int j = 0; j < 8; ++j) ones[j] = (_Float16)1.0f;

  // read-side swizzle (per-thread const): key = (lr>>1)&3
  const int sw = (qd ^ ((lr >> 1) & 3)) * 8;

  f32x4 oacc[4] = {};
  float mrow = -1e30f, lsum = 0.f;

  for (int j0 = 0; j0 < Tn; j0 += 128) {
    // stage K tile (128 j x 64 d) as [kc][row][32], source slot swizzled
#pragma unroll
    for (int p = 0; p < 4; ++p) {
      const int kc = p >> 1, half = p & 1;
      const int row = half * 64 + (tid >> 2);
      const int slot = tid & 3;
      const int sg = slot ^ ((row >> 1) & 3);
      gld16(Kf + ((size_t)bh * Tn + j0 + row) * Dn + kc * 32 + sg * 8,
            &shK[kc * 4096 + (half * 64 + w * 16) * 32]);
    }
    // stage V tile (64 d x 128 t) as [kcv][dd][32], source slot swizzled
#pragma unroll
    for (int p = 0; p < 4; ++p) {
      const int dd = tid >> 2, slot = tid & 3;
      const int sg = slot ^ ((dd >> 1) & 3);
      gld16(Vf + ((size_t)bh * Dn + dd) * Tn + j0 + p * 32 + sg * 8,
            &shV[p * 2048 + (w * 16) * 32]);
    }
    __syncthreads();

    // S^T = mfma(K, Q): lane holds S'[q=lr][k = ct*16 + qd*4 + r]
    f32x4 s2[8];
#pragma unroll
    for (int ct = 0; ct < 8; ++ct) {
      const int rk = ct * 16 + lr;
      s2[ct] = f32x4{0.f, 0.f, 0.f, 0.f};
#pragma unroll
      for (int kc = 0; kc < 2; ++kc) {
        const f16x8 bk = ldh8(&shK[kc * 4096 + rk * 32 + sw]);
        s2[ct] = __builtin_amdgcn_mfma_f32_16x16x32_f16(bk, aq[kc], s2[ct], 0, 0, 0);
      }
    }

    // row-local softmax (log2 domain; Q pre-scaled by 8*log2e)
    float tm = s2[0][0];
#pragma unroll
    for (int ct = 0; ct < 8; ++ct)
#pragma unroll
      for (int r = 0; r < 4; ++r) tm = fmaxf(tm, s2[ct][r]);
    tm = fmaxf(tm, __shfl_xor(tm, 16, 64));
    tm = fmaxf(tm, __shfl_xor(tm, 32, 64));
    const float mn = fmaxf(mrow, tm);
    const float alpha = fexp2(mrow - mn);
    mrow = mn;
#pragma unroll
    for (int ct = 0; ct < 8; ++ct)
#pragma unroll
      for (int r = 0; r < 4; ++r)
        s2[ct][r] = fexp2(s2[ct][r] - mrow);  // arg <= 0
#pragma unroll
    for (int nt = 0; nt < 4; ++nt)
#pragma unroll
      for (int r = 0; r < 4; ++r) oacc[nt][r] *= alpha;

    // PV chunked: per 32-col chunk, pack P rows (2x b64/lane), read A-op
    // fragment back, 4 V-MFMA + rowsum ones-MFMA (same-wave lgkmcnt ordering)
    f32x4 sacc = {};
#pragma unroll
    for (int kcv = 0; kcv < 4; ++kcv) {
#pragma unroll
      for (int c2 = 0; c2 < 2; ++c2) {
        const int ct = kcv * 2 + c2;
        uint2 d2;
        d2.x = pk2(s2[ct][0], s2[ct][1]);
        d2.y = pk2(s2[ct][2], s2[ct][3]);
        *reinterpret_cast<uint2*>(&myP[lr * PS + c2 * 16 + qd * 4]) = d2;
      }
      const f16x8 pa = ldh8(&myP[lr * PS + qd * 8]);
#pragma unroll
      for (int nt = 0; nt < 4; ++nt) {
        const int rv = nt * 16 + lr;
        const f16x8 bv = ldh8(&shV[kcv * 2048 + rv * 32 + sw]);
        oacc[nt] = __builtin_amdgcn_mfma_f32_16x16x32_f16(bv, pa, oacc[nt], 0, 0, 0);
      }
      sacc = __builtin_amdgcn_mfma_f32_16x16x32_f16(ones, pa, sacc, 0, 0, 0);
    }
    lsum = lsum * alpha + sacc[0];
    __syncthreads();
  }

  // epilogue: O^T normalized by per-lane lsum, packed 8B stores
  const int b = bh >> 4, h = bh & 15;
  const float inv = 1.0f / lsum;
  const int q = q0 + w * 16 + lr;
#pragma unroll
  for (int nt = 0; nt < 4; ++nt) {
    unsigned short o[4];
#pragma unroll
    for (int r = 0; r < 4; ++r) o[r] = f2h(oacc[nt][r] * inv);
    const int col = h * 64 + nt * 16 + qd * 4;
    *reinterpret_cast<u16x4*>(&AOf[((size_t)b * Tn + q) * En + col]) =
        u16x4{o[0], o[1], o[2], o[3]};
  }
}

// Out-projection. THIS ROUND: the two fixes proven on gemm_qkv/attn applied
// here too — (a) double-buffered K-loop, 2x-unrolled so buf is compile-time;
// (b) XOR slot-swizzle (64B-row LDS reads had the same half-bank 2x pattern).
// OUT f32; A = AO fp16, B = wout fp16 (pre-cast).
__global__ __launch_bounds__(256) void gemm_out(
    const unsigned short* __restrict__ A, const unsigned short* __restrict__ Bm,
    float* __restrict__ C, int M, int N, int K)
{
  // 2 x (A 4096 | B 4096 shorts) = 32768 B
  __shared__ unsigned short smem[2 * 8192];
  const int tid = threadIdx.x;
  const int w = tid >> 6, L = tid & 63, qd = L >> 4, lr = L & 15;
  const int m0 = blockIdx.y * 128;
  const int n0 = blockIdx.x * 128;
  const int wm = (w >> 1) * 64, wn = (w & 1) * 64;

  size_t aoffs[2], boffs[2];
  int lbase[2];
#pragma unroll
  for (int p = 0; p < 2; ++p) {
    const int c = p * 256 + tid;
    const int row = c >> 2, slot = c & 3;
    const int sg = slot ^ ((row >> 1) & 3);  // swizzled global 16B slot
    aoffs[p] = (size_t)(m0 + row) * K + sg * 8;
    boffs[p] = (size_t)(n0 + row) * K + sg * 8;
    lbase[p] = (p * 4 + w) * 512;
  }
  const int sw = (qd ^ ((lr >> 1) & 3)) * 8;

  f32x4 acc[4][4] = {};

  auto stage = [&](int k0s, int bufbase) {
#pragma unroll
    for (int p = 0; p < 2; ++p) {
      gld16(A + aoffs[p] + k0s, &smem[bufbase + lbase[p]]);
      gld16(Bm + boffs[p] + k0s, &smem[bufbase + 4096 + lbase[p]]);
    }
  };
  auto compute = [&](int cb) {
    f16x8 af[4], bf[4];
#pragma unroll
    for (int mt = 0; mt < 4; ++mt)
      af[mt] = ldh8(&smem[cb + (wm + mt * 16 + lr) * 32 + sw]);
#pragma unroll
    for (int nt = 0; nt < 4; ++nt)
      bf[nt] = ldh8(&smem[cb + 4096 + (wn + nt * 16 + lr) * 32 + sw]);
#pragma unroll
    for (int mt = 0; mt < 4; ++mt)
#pragma unroll
      for (int nt = 0; nt < 4; ++nt)
        acc[mt][nt] = __builtin_amdgcn_mfma_f32_16x16x32_f16(af[mt], bf[nt], acc[mt][nt], 0, 0, 0);
  };

  stage(0, 0);
  __syncthreads();

  for (int k0 = 0; k0 < K; k0 += 64) {
    if (k0 + 32 < K) stage(k0 + 32, 8192);
    compute(0);
    __syncthreads();
    if (k0 + 64 < K) stage(k0 + 64, 0);
    compute(8192);
    __syncthreads();
  }

#pragma unroll
  for (int mt = 0; mt < 4; ++mt)
#pragma unroll
    for (int nt = 0; nt < 4; ++nt)
#pragma unroll
      for (int r = 0; r < 4; ++r) {
        const int m = m0 + wm + mt * 16 + qd * 4 + r;
        const int n = n0 + wn + nt * 16 + lr;
        C[(size_t)m * N + n] = acc[mt][nt][r];
      }
}

extern "C" void kernel_launch(void* const* d_in, const int* in_sizes, int n_in,
                              void* d_out, int out_size, void* d_ws, size_t ws_size,
                              hipStream_t stream) {
  (void)in_sizes; (void)n_in; (void)out_size; (void)ws_size;
  const float* x = (const float*)d_in[0];      // [2,2048,1024] f32
  const float* wqkv = (const float*)d_in[1];   // [3072,1024]  f32
  const float* wout = (const float*)d_in[2];   // [1024,1024]  f32
  float* out = (float*)d_out;                  // [2,2048,1024] f32

  const size_t elems = (size_t)Bn * Hn * Tn * Dn;  // 4M elems (8 MiB fp16)
  unsigned short* Qf = (unsigned short*)d_ws;
  unsigned short* Kf = Qf + elems;
  unsigned short* Vf = Kf + elems;
  unsigned short* AOf = Vf + elems;
  unsigned short* wf = AOf + elems;                // fp16 w_qkv, 3M
  unsigned short* wof = wf + (size_t)3 * En * En;  // fp16 wout, 1M (40 MiB)

  // d_out (16 MiB) doubles as scratch for x hi/lo; overwritten by gemm_out.
  unsigned short* xh = (unsigned short*)d_out;
  unsigned short* xl = xh + elems;

  const int M = Bn * Tn;  // 4096
  dim3 blk(256);
  split_f32_f16<<<dim3((int)(elems / 1024)), blk, 0, stream>>>(x, xh, xl);
  cvt_f32_f16<<<dim3(3 * En * En / 1024), blk, 0, stream>>>(wqkv, wf);
  cvt_f32_f16<<<dim3(En * En / 1024), blk, 0, stream>>>(wout, wof);
  gemm_qkv<<<dim3(24, M / 128), blk, 0, stream>>>(
      xh, xl, wf, Qf, Kf, Vf, M, En);
  attn_kernel<<<dim3(Tn / 64, Bn * Hn), blk, 0, stream>>>(Qf, Kf, Vf, AOf);
  gemm_out<<<dim3(En / 128, M / 128), blk, 0, stream>>>(
      AOf, wof, out, M, En, En);
}

// Round 17
// 227.793 us; speedup vs baseline: 1.0591x; 1.0591x over previous
//
#include <hip/hip_runtime.h>
#include <hip/hip_bf16.h>

typedef _Float16 f16x8 __attribute__((ext_vector_type(8)));
typedef unsigned short u16x8 __attribute__((ext_vector_type(8)));
typedef unsigned short u16x4 __attribute__((ext_vector_type(4)));
typedef float f32x4 __attribute__((ext_vector_type(4)));

static constexpr int Bn = 2;
static constexpr int Tn = 2048;
static constexpr int En = 1024;
static constexpr int Hn = 16;
static constexpr int Dn = 64;
#define LOG2E 1.44269504088896340736f

static constexpr int TS = 136;  // qkv epilogue transpose stride
static constexpr int PS = 40;   // attn P-chunk row stride (shorts)

__device__ __forceinline__ unsigned short f2h(float x) {
  _Float16 h = (_Float16)x;
  return __builtin_bit_cast(unsigned short, h);
}
__device__ __forceinline__ float h2f(unsigned short u) {
  return (float)__builtin_bit_cast(_Float16, u);
}
__device__ __forceinline__ f16x8 ldh8(const unsigned short* p) {
  return __builtin_bit_cast(f16x8, *reinterpret_cast<const u16x8*>(p));
}
__device__ __forceinline__ unsigned int pk2(float a, float b) {
  return __builtin_bit_cast(unsigned int, __builtin_amdgcn_cvt_pkrtz(a, b));
}
// raw v_exp_f32 (2^x, one VALU inst); args <= 0, flush-to-zero is wanted
__device__ __forceinline__ float fexp2(float x) {
  return __builtin_amdgcn_exp2f(x);
}
// async global->LDS, 16B/lane; LDS dest must be wave-uniform base (+lane*16)
__device__ __forceinline__ void gld16(const void* g, void* l) {
  __builtin_amdgcn_global_load_lds(
      (__attribute__((address_space(1))) void*)(const_cast<void*>(g)),
      (__attribute__((address_space(3))) void*)(l), 16, 0, 0);
}

// fp16 hi/lo split: (hi + lo) == x to ~22 mantissa bits
__global__ __launch_bounds__(256) void split_f32_f16(
    const float* __restrict__ src, unsigned short* __restrict__ hi,
    unsigned short* __restrict__ lo)
{
  const int i = (blockIdx.x * 256 + threadIdx.x) * 4;
  const float4 v = *reinterpret_cast<const float4*>(src + i);
  ushort4 h, l;
  h.x = f2h(v.x); l.x = f2h(v.x - h2f(h.x));
  h.y = f2h(v.y); l.y = f2h(v.y - h2f(h.y));
  h.z = f2h(v.z); l.z = f2h(v.z - h2f(h.z));
  h.w = f2h(v.w); l.w = f2h(v.w - h2f(h.w));
  *reinterpret_cast<ushort4*>(hi + i) = h;
  *reinterpret_cast<ushort4*>(lo + i) = l;
}

__global__ __launch_bounds__(256) void cvt_f32_f16(
    const float* __restrict__ src, unsigned short* __restrict__ dst)
{
  const int i = (blockIdx.x * 256 + threadIdx.x) * 4;
  const float4 v = *reinterpret_cast<const float4*>(src + i);
  ushort4 u;
  u.x = f2h(v.x); u.y = f2h(v.y); u.z = f2h(v.z); u.w = f2h(v.w);
  *reinterpret_cast<ushort4*>(dst + i) = u;
}

// QKV GEMM, fp16 — REVERTED to r15 (measured 72 us, 96 VGPR, occ 15.5%).
// r16's 2x unroll (compile-time buf) inflated VGPR 96->136, occupancy
// 15.5->10.4%, dur 72->86: this kernel is occupancy-fragile; the rolled
// loop's addr VALU hides under co-resident blocks. dbuf + XOR slot-swizzle.
__global__ __launch_bounds__(256) void gemm_qkv(
    const unsigned short* __restrict__ xh, const unsigned short* __restrict__ xl,
    const unsigned short* __restrict__ wf,
    unsigned short* __restrict__ Qf, unsigned short* __restrict__ Kf,
    unsigned short* __restrict__ Vf, int M, int K)
{
  // 2 x (Ah 4096 | Al 4096 | B 4096 shorts) = 49152 B; epilogue reuses [0..17408)
  __shared__ unsigned short smem[2 * 12288];

  const int tid = threadIdx.x;
  const int w = tid >> 6, L = tid & 63, qd = L >> 4, lr = L & 15;
  const int m0 = blockIdx.y * 128;
  const int kk = blockIdx.x >> 3;          // 0=Q 1=K 2=V (uniform per block)
  const int hh0 = (blockIdx.x & 7) * 2;    // two heads per block
  const int wm = (w >> 1) * 64, wn = (w & 1) * 64;

  size_t aoffs[2], boffs[2];
  int lbase[2];
#pragma unroll
  for (int p = 0; p < 2; ++p) {
    const int c = p * 256 + tid;
    const int row = c >> 2, slot = c & 3;
    const int dd = row & 63, hl = row >> 6;
    const int sg = slot ^ ((row >> 1) & 3);  // swizzled global 16B slot
    aoffs[p] = (size_t)(m0 + row) * K + sg * 8;
    boffs[p] = (size_t)(dd * 48 + kk * 16 + hh0 + hl) * K + sg * 8;
    lbase[p] = (p * 4 + w) * 512;  // wave-uniform LDS base (shorts)
  }

  f32x4 acc[4][4] = {};

  // prologue: stage tile 0 into buf 0
#pragma unroll
  for (int p = 0; p < 2; ++p) {
    gld16(xh + aoffs[p], &smem[lbase[p]]);
    gld16(wf + boffs[p], &smem[8192 + lbase[p]]);
    if (kk < 2) gld16(xl + aoffs[p], &smem[4096 + lbase[p]]);
  }
  __syncthreads();

  // read-side swizzle: per-thread const, key = (lr>>1)&3
  const int sw = (qd ^ ((lr >> 1) & 3)) * 8;

  int buf = 0;
  for (int k0 = 0; k0 < K; k0 += 32) {
    if (k0 + 32 < K) {
      const int nb = (buf ^ 1) * 12288;
#pragma unroll
      for (int p = 0; p < 2; ++p) {
        gld16(xh + aoffs[p] + k0 + 32, &smem[nb + lbase[p]]);
        gld16(wf + boffs[p] + k0 + 32, &smem[nb + 8192 + lbase[p]]);
        if (kk < 2) gld16(xl + aoffs[p] + k0 + 32, &smem[nb + 4096 + lbase[p]]);
      }
    }

    const int cb = buf * 12288;
    f16x8 afh[4], bf[4];
#pragma unroll
    for (int mt = 0; mt < 4; ++mt)
      afh[mt] = ldh8(&smem[cb + (wm + mt * 16 + lr) * 32 + sw]);
#pragma unroll
    for (int nt = 0; nt < 4; ++nt)
      bf[nt] = ldh8(&smem[cb + 8192 + (wn + nt * 16 + lr) * 32 + sw]);
    if (kk < 2) {
      f16x8 afl[4];
#pragma unroll
      for (int mt = 0; mt < 4; ++mt)
        afl[mt] = ldh8(&smem[cb + 4096 + (wm + mt * 16 + lr) * 32 + sw]);
#pragma unroll
      for (int mt = 0; mt < 4; ++mt)
#pragma unroll
        for (int nt = 0; nt < 4; ++nt) {
          acc[mt][nt] = __builtin_amdgcn_mfma_f32_16x16x32_f16(afh[mt], bf[nt], acc[mt][nt], 0, 0, 0);
          acc[mt][nt] = __builtin_amdgcn_mfma_f32_16x16x32_f16(afl[mt], bf[nt], acc[mt][nt], 0, 0, 0);
        }
    } else {
#pragma unroll
      for (int mt = 0; mt < 4; ++mt)
#pragma unroll
        for (int nt = 0; nt < 4; ++nt)
          acc[mt][nt] = __builtin_amdgcn_mfma_f32_16x16x32_f16(afh[mt], bf[nt], acc[mt][nt], 0, 0, 0);
    }
    __syncthreads();
    buf ^= 1;
  }

  // epilogue: fp16 into LDS transpose buffer -> coalesced 16B stores
  const int b = m0 >> 11;
  const int t0 = m0 & (Tn - 1);
  const float qscale = (kk == 0) ? 8.0f * LOG2E : 1.0f;
#pragma unroll
  for (int mt = 0; mt < 4; ++mt)
#pragma unroll
    for (int nt = 0; nt < 4; ++nt)
#pragma unroll
      for (int r = 0; r < 4; ++r) {
        const int ml = wm + mt * 16 + qd * 4 + r;  // C/D row=(lane>>4)*4+reg
        const int cl = wn + nt * 16 + lr;          // C/D col=lane&15
        smem[ml * TS + cl] = f2h(acc[mt][nt][r] * qscale);
      }
  __syncthreads();

  unsigned short* dst = (kk == 0) ? Qf : (kk == 1) ? Kf : Vf;
  if (kk < 2) {
#pragma unroll
    for (int p = 0; p < 8; ++p) {
      const int s = p * 256 + tid;
      const int tl = s >> 4, sub = s & 15;
      const int hl = sub >> 3, oct = sub & 7;
      const u16x8 v = *reinterpret_cast<const u16x8*>(&smem[tl * TS + hl * 64 + oct * 8]);
      *reinterpret_cast<u16x8*>(
          dst + ((size_t)(b * Hn + hh0 + hl) * Tn + t0 + tl) * Dn + oct * 8) = v;
    }
  } else {
#pragma unroll
    for (int p = 0; p < 8; ++p) {
      const int s = p * 256 + tid;
      const int cl = s >> 4, oct = s & 15;
      const int hl = cl >> 6, dd = cl & 63;
      u16x8 v;
#pragma unroll
      for (int j = 0; j < 8; ++j) v[j] = smem[(oct * 8 + j) * TS + cl];
      *reinterpret_cast<u16x8*>(
          dst + ((size_t)((b * Hn + hh0 + hl) * Dn + dd)) * Tn + t0 + oct * 8) = v;
    }
  }
}

// Flash attention (r15 measured-good, unchanged): LDS-staged K/V with XOR
// slot-swizzle, swapped-operand QK^T, log2-domain softmax with raw v_exp,
// chunked packed P, O^T epilogue.
// Qf(x8*log2e),Kf: [b,h,t,d]  Vf: [b,h,d,t]  AO: fp16.
__global__ __launch_bounds__(256, 2) void attn_kernel(
    const unsigned short* __restrict__ Qf, const unsigned short* __restrict__ Kf,
    const unsigned short* __restrict__ Vf, unsigned short* __restrict__ AOf)
{
  __shared__ unsigned short shK[2 * 128 * 32];  // [kc][j row][32]  16 KB
  __shared__ unsigned short shV[4 * 64 * 32];   // [kcv][dd][32]    16 KB
  __shared__ unsigned short shP[4 * 16 * PS];   // per-wave 16x32 chunk, 5 KB
  const int tid = threadIdx.x;
  const int w = tid >> 6, L = tid & 63, qd = L >> 4, lr = L & 15;
  const int q0 = blockIdx.x * 64;
  const int bh = blockIdx.y;
  unsigned short* myP = &shP[w * 16 * PS];

  f16x8 aq[2];
  {
    const size_t qoff = ((size_t)bh * Tn + q0 + w * 16 + lr) * Dn;
    aq[0] = ldh8(Qf + qoff + qd * 8);
    aq[1] = ldh8(Qf + qoff + 32 + qd * 8);
  }
  f16x8 ones;
#pragma unroll
  for (int j = 0; j < 8; ++j) ones[j] = (_Float16)1.0f;

  // read-side swizzle (per-thread const): key = (lr>>1)&3
  const int sw = (qd ^ ((lr >> 1) & 3)) * 8;

  f32x4 oacc[4] = {};
  float mrow = -1e30f, lsum = 0.f;

  for (int j0 = 0; j0 < Tn; j0 += 128) {
    // stage K tile (128 j x 64 d) as [kc][row][32], source slot swizzled
#pragma unroll
    for (int p = 0; p < 4; ++p) {
      const int kc = p >> 1, half = p & 1;
      const int row = half * 64 + (tid >> 2);
      const int slot = tid & 3;
      const int sg = slot ^ ((row >> 1) & 3);
      gld16(Kf + ((size_t)bh * Tn + j0 + row) * Dn + kc * 32 + sg * 8,
            &shK[kc * 4096 + (half * 64 + w * 16) * 32]);
    }
    // stage V tile (64 d x 128 t) as [kcv][dd][32], source slot swizzled
#pragma unroll
    for (int p = 0; p < 4; ++p) {
      const int dd = tid >> 2, slot = tid & 3;
      const int sg = slot ^ ((dd >> 1) & 3);
      gld16(Vf + ((size_t)bh * Dn + dd) * Tn + j0 + p * 32 + sg * 8,
            &shV[p * 2048 + (w * 16) * 32]);
    }
    __syncthreads();

    // S^T = mfma(K, Q): lane holds S'[q=lr][k = ct*16 + qd*4 + r]
    f32x4 s2[8];
#pragma unroll
    for (int ct = 0; ct < 8; ++ct) {
      const int rk = ct * 16 + lr;
      s2[ct] = f32x4{0.f, 0.f, 0.f, 0.f};
#pragma unroll
      for (int kc = 0; kc < 2; ++kc) {
        const f16x8 bk = ldh8(&shK[kc * 4096 + rk * 32 + sw]);
        s2[ct] = __builtin_amdgcn_mfma_f32_16x16x32_f16(bk, aq[kc], s2[ct], 0, 0, 0);
      }
    }

    // row-local softmax (log2 domain; Q pre-scaled by 8*log2e)
    float tm = s2[0][0];
#pragma unroll
    for (int ct = 0; ct < 8; ++ct)
#pragma unroll
      for (int r = 0; r < 4; ++r) tm = fmaxf(tm, s2[ct][r]);
    tm = fmaxf(tm, __shfl_xor(tm, 16, 64));
    tm = fmaxf(tm, __shfl_xor(tm, 32, 64));
    const float mn = fmaxf(mrow, tm);
    const float alpha = fexp2(mrow - mn);
    mrow = mn;
#pragma unroll
    for (int ct = 0; ct < 8; ++ct)
#pragma unroll
      for (int r = 0; r < 4; ++r)
        s2[ct][r] = fexp2(s2[ct][r] - mrow);  // arg <= 0
#pragma unroll
    for (int nt = 0; nt < 4; ++nt)
#pragma unroll
      for (int r = 0; r < 4; ++r) oacc[nt][r] *= alpha;

    // PV chunked: per 32-col chunk, pack P rows (2x b64/lane), read A-op
    // fragment back, 4 V-MFMA + rowsum ones-MFMA (same-wave lgkmcnt ordering)
    f32x4 sacc = {};
#pragma unroll
    for (int kcv = 0; kcv < 4; ++kcv) {
#pragma unroll
      for (int c2 = 0; c2 < 2; ++c2) {
        const int ct = kcv * 2 + c2;
        uint2 d2;
        d2.x = pk2(s2[ct][0], s2[ct][1]);
        d2.y = pk2(s2[ct][2], s2[ct][3]);
        *reinterpret_cast<uint2*>(&myP[lr * PS + c2 * 16 + qd * 4]) = d2;
      }
      const f16x8 pa = ldh8(&myP[lr * PS + qd * 8]);
#pragma unroll
      for (int nt = 0; nt < 4; ++nt) {
        const int rv = nt * 16 + lr;
        const f16x8 bv = ldh8(&shV[kcv * 2048 + rv * 32 + sw]);
        oacc[nt] = __builtin_amdgcn_mfma_f32_16x16x32_f16(bv, pa, oacc[nt], 0, 0, 0);
      }
      sacc = __builtin_amdgcn_mfma_f32_16x16x32_f16(ones, pa, sacc, 0, 0, 0);
    }
    lsum = lsum * alpha + sacc[0];
    __syncthreads();
  }

  // epilogue: O^T normalized by per-lane lsum, packed 8B stores
  const int b = bh >> 4, h = bh & 15;
  const float inv = 1.0f / lsum;
  const int q = q0 + w * 16 + lr;
#pragma unroll
  for (int nt = 0; nt < 4; ++nt) {
    unsigned short o[4];
#pragma unroll
    for (int r = 0; r < 4; ++r) o[r] = f2h(oacc[nt][r] * inv);
    const int col = h * 64 + nt * 16 + qd * 4;
    *reinterpret_cast<u16x4*>(&AOf[((size_t)b * Tn + q) * En + col]) =
        u16x4{o[0], o[1], o[2], o[3]};
  }
}

// Out-projection (kept from r16 for attribution: dbuf + XOR slot-swizzle,
// 2x-unrolled compile-time buf — small kernel, only 2 LDS buffers and no
// hi/lo third stream, so the unroll's VGPR cost is modest here).
// OUT f32; A = AO fp16, B = wout fp16 (pre-cast).
__global__ __launch_bounds__(256) void gemm_out(
    const unsigned short* __restrict__ A, const unsigned short* __restrict__ Bm,
    float* __restrict__ C, int M, int N, int K)
{
  // 2 x (A 4096 | B 4096 shorts) = 32768 B
  __shared__ unsigned short smem[2 * 8192];
  const int tid = threadIdx.x;
  const int w = tid >> 6, L = tid & 63, qd = L >> 4, lr = L & 15;
  const int m0 = blockIdx.y * 128;
  const int n0 = blockIdx.x * 128;
  const int wm = (w >> 1) * 64, wn = (w & 1) * 64;

  size_t aoffs[2], boffs[2];
  int lbase[2];
#pragma unroll
  for (int p = 0; p < 2; ++p) {
    const int c = p * 256 + tid;
    const int row = c >> 2, slot = c & 3;
    const int sg = slot ^ ((row >> 1) & 3);  // swizzled global 16B slot
    aoffs[p] = (size_t)(m0 + row) * K + sg * 8;
    boffs[p] = (size_t)(n0 + row) * K + sg * 8;
    lbase[p] = (p * 4 + w) * 512;
  }
  const int sw = (qd ^ ((lr >> 1) & 3)) * 8;

  f32x4 acc[4][4] = {};

  auto stage = [&](int k0s, int bufbase) {
#pragma unroll
    for (int p = 0; p < 2; ++p) {
      gld16(A + aoffs[p] + k0s, &smem[bufbase + lbase[p]]);
      gld16(Bm + boffs[p] + k0s, &smem[bufbase + 4096 + lbase[p]]);
    }
  };
  auto compute = [&](int cb) {
    f16x8 af[4], bf[4];
#pragma unroll
    for (int mt = 0; mt < 4; ++mt)
      af[mt] = ldh8(&smem[cb + (wm + mt * 16 + lr) * 32 + sw]);
#pragma unroll
    for (int nt = 0; nt < 4; ++nt)
      bf[nt] = ldh8(&smem[cb + 4096 + (wn + nt * 16 + lr) * 32 + sw]);
#pragma unroll
    for (int mt = 0; mt < 4; ++mt)
#pragma unroll
      for (int nt = 0; nt < 4; ++nt)
        acc[mt][nt] = __builtin_amdgcn_mfma_f32_16x16x32_f16(af[mt], bf[nt], acc[mt][nt], 0, 0, 0);
  };

  stage(0, 0);
  __syncthreads();

  for (int k0 = 0; k0 < K; k0 += 64) {
    if (k0 + 32 < K) stage(k0 + 32, 8192);
    compute(0);
    __syncthreads();
    if (k0 + 64 < K) stage(k0 + 64, 0);
    compute(8192);
    __syncthreads();
  }

#pragma unroll
  for (int mt = 0; mt < 4; ++mt)
#pragma unroll
    for (int nt = 0; nt < 4; ++nt)
#pragma unroll
      for (int r = 0; r < 4; ++r) {
        const int m = m0 + wm + mt * 16 + qd * 4 + r;
        const int n = n0 + wn + nt * 16 + lr;
        C[(size_t)m * N + n] = acc[mt][nt][r];
      }
}

extern "C" void kernel_launch(void* const* d_in, const int* in_sizes, int n_in,
                              void* d_out, int out_size, void* d_ws, size_t ws_size,
                              hipStream_t stream) {
  (void)in_sizes; (void)n_in; (void)out_size; (void)ws_size;
  const float* x = (const float*)d_in[0];      // [2,2048,1024] f32
  const float* wqkv = (const float*)d_in[1];   // [3072,1024]  f32
  const float* wout = (const float*)d_in[2];   // [1024,1024]  f32
  float* out = (float*)d_out;                  // [2,2048,1024] f32

  const size_t elems = (size_t)Bn * Hn * Tn * Dn;  // 4M elems (8 MiB fp16)
  unsigned short* Qf = (unsigned short*)d_ws;
  unsigned short* Kf = Qf + elems;
  unsigned short* Vf = Kf + elems;
  unsigned short* AOf = Vf + elems;
  unsigned short* wf = AOf + elems;                // fp16 w_qkv, 3M
  unsigned short* wof = wf + (size_t)3 * En * En;  // fp16 wout, 1M (40 MiB)

  // d_out (16 MiB) doubles as scratch for x hi/lo; overwritten by gemm_out.
  unsigned short* xh = (unsigned short*)d_out;
  unsigned short* xl = xh + elems;

  const int M = Bn * Tn;  // 4096
  dim3 blk(256);
  split_f32_f16<<<dim3((int)(elems / 1024)), blk, 0, stream>>>(x, xh, xl);
  cvt_f32_f16<<<dim3(3 * En * En / 1024), blk, 0, stream>>>(wqkv, wf);
  cvt_f32_f16<<<dim3(En * En / 1024), blk, 0, stream>>>(wout, wof);
  gemm_qkv<<<dim3(24, M / 128), blk, 0, stream>>>(
      xh, xl, wf, Qf, Kf, Vf, M, En);
  attn_kernel<<<dim3(Tn / 64, Bn * Hn), blk, 0, stream>>>(Qf, Kf, Vf, AOf);
  gemm_out<<<dim3(En / 128, M / 128), blk, 0, stream>>>(
      AOf, wof, out, M, En, En);
}

// Round 18
// 224.815 us; speedup vs baseline: 1.0731x; 1.0132x over previous
//
#include <hip/hip_runtime.h>
#include <hip/hip_bf16.h>

typedef _Float16 f16x8 __attribute__((ext_vector_type(8)));
typedef unsigned short u16x8 __attribute__((ext_vector_type(8)));
typedef unsigned short u16x4 __attribute__((ext_vector_type(4)));
typedef float f32x4 __attribute__((ext_vector_type(4)));

static constexpr int Bn = 2;
static constexpr int Tn = 2048;
static constexpr int En = 1024;
static constexpr int Hn = 16;
static constexpr int Dn = 64;
#define LOG2E 1.44269504088896340736f

static constexpr int TS = 136;  // qkv epilogue transpose stride
static constexpr int PS = 40;   // attn P-chunk row stride (shorts)

__device__ __forceinline__ unsigned short f2h(float x) {
  _Float16 h = (_Float16)x;
  return __builtin_bit_cast(unsigned short, h);
}
__device__ __forceinline__ float h2f(unsigned short u) {
  return (float)__builtin_bit_cast(_Float16, u);
}
__device__ __forceinline__ f16x8 ldh8(const unsigned short* p) {
  return __builtin_bit_cast(f16x8, *reinterpret_cast<const u16x8*>(p));
}
__device__ __forceinline__ unsigned int pk2(float a, float b) {
  return __builtin_bit_cast(unsigned int, __builtin_amdgcn_cvt_pkrtz(a, b));
}
// raw v_exp_f32 (2^x, one VALU inst); args <= 0, flush-to-zero is wanted
__device__ __forceinline__ float fexp2(float x) {
  return __builtin_amdgcn_exp2f(x);
}
// async global->LDS, 16B/lane; LDS dest must be wave-uniform base (+lane*16)
__device__ __forceinline__ void gld16(const void* g, void* l) {
  __builtin_amdgcn_global_load_lds(
      (__attribute__((address_space(1))) void*)(const_cast<void*>(g)),
      (__attribute__((address_space(3))) void*)(l), 16, 0, 0);
}

// Fused conversions (was 3 kernels -> 1: saves 2 launch gaps).
// Blocks [0,4096): x f32 -> fp16 hi+lo split (exact to ~22 bits).
// Blocks [4096,7168): w_qkv -> fp16. Blocks [7168,8192): w_out -> fp16.
__global__ __launch_bounds__(256) void prep(
    const float* __restrict__ x, const float* __restrict__ wqkv,
    const float* __restrict__ wout,
    unsigned short* __restrict__ xh, unsigned short* __restrict__ xl,
    unsigned short* __restrict__ wf, unsigned short* __restrict__ wof)
{
  const int b = blockIdx.x;
  if (b < 4096) {
    const int i = (b * 256 + threadIdx.x) * 4;
    const float4 v = *reinterpret_cast<const float4*>(x + i);
    ushort4 h, l;
    h.x = f2h(v.x); l.x = f2h(v.x - h2f(h.x));
    h.y = f2h(v.y); l.y = f2h(v.y - h2f(h.y));
    h.z = f2h(v.z); l.z = f2h(v.z - h2f(h.z));
    h.w = f2h(v.w); l.w = f2h(v.w - h2f(h.w));
    *reinterpret_cast<ushort4*>(xh + i) = h;
    *reinterpret_cast<ushort4*>(xl + i) = l;
  } else if (b < 7168) {
    const int i = ((b - 4096) * 256 + threadIdx.x) * 4;
    const float4 v = *reinterpret_cast<const float4*>(wqkv + i);
    ushort4 u;
    u.x = f2h(v.x); u.y = f2h(v.y); u.z = f2h(v.z); u.w = f2h(v.w);
    *reinterpret_cast<ushort4*>(wf + i) = u;
  } else {
    const int i = ((b - 7168) * 256 + threadIdx.x) * 4;
    const float4 v = *reinterpret_cast<const float4*>(wout + i);
    ushort4 u;
    u.x = f2h(v.x); u.y = f2h(v.y); u.z = f2h(v.z); u.w = f2h(v.w);
    *reinterpret_cast<ushort4*>(wof + i) = u;
  }
}

// QKV GEMM, fp16 (r15 structure: dbuf + XOR slot-swizzle, rolled loop).
// THIS ROUND: grid dims swapped to (m0, colgroup). XCD = linear_id % 8 =
// blockIdx.x % 8, so the 24 blocks sharing one m0's A rows (512 KB hi+lo)
// co-locate on one XCD L2 (was spread -> every L2 refetched all of A;
// FETCH 73.9 MB vs ~46 ideal).
__global__ __launch_bounds__(256) void gemm_qkv(
    const unsigned short* __restrict__ xh, const unsigned short* __restrict__ xl,
    const unsigned short* __restrict__ wf,
    unsigned short* __restrict__ Qf, unsigned short* __restrict__ Kf,
    unsigned short* __restrict__ Vf, int M, int K)
{
  // 2 x (Ah 4096 | Al 4096 | B 4096 shorts) = 49152 B; epilogue reuses [0..17408)
  __shared__ unsigned short smem[2 * 12288];

  const int tid = threadIdx.x;
  const int w = tid >> 6, L = tid & 63, qd = L >> 4, lr = L & 15;
  const int m0 = blockIdx.x * 128;         // swapped: m0 on fast dim
  const int kk = blockIdx.y >> 3;          // 0=Q 1=K 2=V (uniform per block)
  const int hh0 = (blockIdx.y & 7) * 2;    // two heads per block
  const int wm = (w >> 1) * 64, wn = (w & 1) * 64;

  size_t aoffs[2], boffs[2];
  int lbase[2];
#pragma unroll
  for (int p = 0; p < 2; ++p) {
    const int c = p * 256 + tid;
    const int row = c >> 2, slot = c & 3;
    const int dd = row & 63, hl = row >> 6;
    const int sg = slot ^ ((row >> 1) & 3);  // swizzled global 16B slot
    aoffs[p] = (size_t)(m0 + row) * K + sg * 8;
    boffs[p] = (size_t)(dd * 48 + kk * 16 + hh0 + hl) * K + sg * 8;
    lbase[p] = (p * 4 + w) * 512;  // wave-uniform LDS base (shorts)
  }

  f32x4 acc[4][4] = {};

  // prologue: stage tile 0 into buf 0
#pragma unroll
  for (int p = 0; p < 2; ++p) {
    gld16(xh + aoffs[p], &smem[lbase[p]]);
    gld16(wf + boffs[p], &smem[8192 + lbase[p]]);
    if (kk < 2) gld16(xl + aoffs[p], &smem[4096 + lbase[p]]);
  }
  __syncthreads();

  // read-side swizzle: per-thread const, key = (lr>>1)&3
  const int sw = (qd ^ ((lr >> 1) & 3)) * 8;

  int buf = 0;
  for (int k0 = 0; k0 < K; k0 += 32) {
    if (k0 + 32 < K) {
      const int nb = (buf ^ 1) * 12288;
#pragma unroll
      for (int p = 0; p < 2; ++p) {
        gld16(xh + aoffs[p] + k0 + 32, &smem[nb + lbase[p]]);
        gld16(wf + boffs[p] + k0 + 32, &smem[nb + 8192 + lbase[p]]);
        if (kk < 2) gld16(xl + aoffs[p] + k0 + 32, &smem[nb + 4096 + lbase[p]]);
      }
    }

    const int cb = buf * 12288;
    f16x8 afh[4], bf[4];
#pragma unroll
    for (int mt = 0; mt < 4; ++mt)
      afh[mt] = ldh8(&smem[cb + (wm + mt * 16 + lr) * 32 + sw]);
#pragma unroll
    for (int nt = 0; nt < 4; ++nt)
      bf[nt] = ldh8(&smem[cb + 8192 + (wn + nt * 16 + lr) * 32 + sw]);
    if (kk < 2) {
      f16x8 afl[4];
#pragma unroll
      for (int mt = 0; mt < 4; ++mt)
        afl[mt] = ldh8(&smem[cb + 4096 + (wm + mt * 16 + lr) * 32 + sw]);
#pragma unroll
      for (int mt = 0; mt < 4; ++mt)
#pragma unroll
        for (int nt = 0; nt < 4; ++nt) {
          acc[mt][nt] = __builtin_amdgcn_mfma_f32_16x16x32_f16(afh[mt], bf[nt], acc[mt][nt], 0, 0, 0);
          acc[mt][nt] = __builtin_amdgcn_mfma_f32_16x16x32_f16(afl[mt], bf[nt], acc[mt][nt], 0, 0, 0);
        }
    } else {
#pragma unroll
      for (int mt = 0; mt < 4; ++mt)
#pragma unroll
        for (int nt = 0; nt < 4; ++nt)
          acc[mt][nt] = __builtin_amdgcn_mfma_f32_16x16x32_f16(afh[mt], bf[nt], acc[mt][nt], 0, 0, 0);
    }
    __syncthreads();
    buf ^= 1;
  }

  // epilogue: fp16 into LDS transpose buffer -> coalesced 16B stores
  const int b = m0 >> 11;
  const int t0 = m0 & (Tn - 1);
  const float qscale = (kk == 0) ? 8.0f * LOG2E : 1.0f;
#pragma unroll
  for (int mt = 0; mt < 4; ++mt)
#pragma unroll
    for (int nt = 0; nt < 4; ++nt)
#pragma unroll
      for (int r = 0; r < 4; ++r) {
        const int ml = wm + mt * 16 + qd * 4 + r;  // C/D row=(lane>>4)*4+reg
        const int cl = wn + nt * 16 + lr;          // C/D col=lane&15
        smem[ml * TS + cl] = f2h(acc[mt][nt][r] * qscale);
      }
  __syncthreads();

  unsigned short* dst = (kk == 0) ? Qf : (kk == 1) ? Kf : Vf;
  if (kk < 2) {
#pragma unroll
    for (int p = 0; p < 8; ++p) {
      const int s = p * 256 + tid;
      const int tl = s >> 4, sub = s & 15;
      const int hl = sub >> 3, oct = sub & 7;
      const u16x8 v = *reinterpret_cast<const u16x8*>(&smem[tl * TS + hl * 64 + oct * 8]);
      *reinterpret_cast<u16x8*>(
          dst + ((size_t)(b * Hn + hh0 + hl) * Tn + t0 + tl) * Dn + oct * 8) = v;
    }
  } else {
#pragma unroll
    for (int p = 0; p < 8; ++p) {
      const int s = p * 256 + tid;
      const int cl = s >> 4, oct = s & 15;
      const int hl = cl >> 6, dd = cl & 63;
      u16x8 v;
#pragma unroll
      for (int j = 0; j < 8; ++j) v[j] = smem[(oct * 8 + j) * TS + cl];
      *reinterpret_cast<u16x8*>(
          dst + ((size_t)((b * Hn + hh0 + hl) * Dn + dd)) * Tn + t0 + oct * 8) = v;
    }
  }
}

// Flash attention (r15 structure). THIS ROUND: grid dims swapped to
// (bh, q-block). XCD = linear_id % 8 = bh % 8, so all 32 q-blocks sharing
// one head's K/V (512 KB) co-locate on one XCD L2: 4 heads x 512 KB = 2 MB
// working set per 4 MB L2 (was: every L2 saw all 32 heads = 16 MB -> thrash;
// FETCH 69.7 MB vs 16 MB ideal).
// Qf(x8*log2e),Kf: [b,h,t,d]  Vf: [b,h,d,t]  AO: fp16, O^T epilogue.
__global__ __launch_bounds__(256, 2) void attn_kernel(
    const unsigned short* __restrict__ Qf, const unsigned short* __restrict__ Kf,
    const unsigned short* __restrict__ Vf, unsigned short* __restrict__ AOf)
{
  __shared__ unsigned short shK[2 * 128 * 32];  // [kc][j row][32]  16 KB
  __shared__ unsigned short shV[4 * 64 * 32];   // [kcv][dd][32]    16 KB
  __shared__ unsigned short shP[4 * 16 * PS];   // per-wave 16x32 chunk, 5 KB
  const int tid = threadIdx.x;
  const int w = tid >> 6, L = tid & 63, qd = L >> 4, lr = L & 15;
  const int bh = blockIdx.x;                 // swapped: bh on fast dim
  const int q0 = blockIdx.y * 64;
  unsigned short* myP = &shP[w * 16 * PS];

  f16x8 aq[2];
  {
    const size_t qoff = ((size_t)bh * Tn + q0 + w * 16 + lr) * Dn;
    aq[0] = ldh8(Qf + qoff + qd * 8);
    aq[1] = ldh8(Qf + qoff + 32 + qd * 8);
  }
  f16x8 ones;
#pragma unroll
  for (int j = 0; j < 8; ++j) ones[j] = (_Float16)1.0f;

  // read-side swizzle (per-thread const): key = (lr>>1)&3
  const int sw = (qd ^ ((lr >> 1) & 3)) * 8;

  f32x4 oacc[4] = {};
  float mrow = -1e30f, lsum = 0.f;

  for (int j0 = 0; j0 < Tn; j0 += 128) {
    // stage K tile (128 j x 64 d) as [kc][row][32], source slot swizzled
#pragma unroll
    for (int p = 0; p < 4; ++p) {
      const int kc = p >> 1, half = p & 1;
      const int row = half * 64 + (tid >> 2);
      const int slot = tid & 3;
      const int sg = slot ^ ((row >> 1) & 3);
      gld16(Kf + ((size_t)bh * Tn + j0 + row) * Dn + kc * 32 + sg * 8,
            &shK[kc * 4096 + (half * 64 + w * 16) * 32]);
    }
    // stage V tile (64 d x 128 t) as [kcv][dd][32], source slot swizzled
#pragma unroll
    for (int p = 0; p < 4; ++p) {
      const int dd = tid >> 2, slot = tid & 3;
      const int sg = slot ^ ((dd >> 1) & 3);
      gld16(Vf + ((size_t)bh * Dn + dd) * Tn + j0 + p * 32 + sg * 8,
            &shV[p * 2048 + (w * 16) * 32]);
    }
    __syncthreads();

    // S^T = mfma(K, Q): lane holds S'[q=lr][k = ct*16 + qd*4 + r]
    f32x4 s2[8];
#pragma unroll
    for (int ct = 0; ct < 8; ++ct) {
      const int rk = ct * 16 + lr;
      s2[ct] = f32x4{0.f, 0.f, 0.f, 0.f};
#pragma unroll
      for (int kc = 0; kc < 2; ++kc) {
        const f16x8 bk = ldh8(&shK[kc * 4096 + rk * 32 + sw]);
        s2[ct] = __builtin_amdgcn_mfma_f32_16x16x32_f16(bk, aq[kc], s2[ct], 0, 0, 0);
      }
    }

    // row-local softmax (log2 domain; Q pre-scaled by 8*log2e)
    float tm = s2[0][0];
#pragma unroll
    for (int ct = 0; ct < 8; ++ct)
#pragma unroll
      for (int r = 0; r < 4; ++r) tm = fmaxf(tm, s2[ct][r]);
    tm = fmaxf(tm, __shfl_xor(tm, 16, 64));
    tm = fmaxf(tm, __shfl_xor(tm, 32, 64));
    const float mn = fmaxf(mrow, tm);
    const float alpha = fexp2(mrow - mn);
    mrow = mn;
#pragma unroll
    for (int ct = 0; ct < 8; ++ct)
#pragma unroll
      for (int r = 0; r < 4; ++r)
        s2[ct][r] = fexp2(s2[ct][r] - mrow);  // arg <= 0
#pragma unroll
    for (int nt = 0; nt < 4; ++nt)
#pragma unroll
      for (int r = 0; r < 4; ++r) oacc[nt][r] *= alpha;

    // PV chunked: per 32-col chunk, pack P rows (2x b64/lane), read A-op
    // fragment back, 4 V-MFMA + rowsum ones-MFMA (same-wave lgkmcnt ordering)
    f32x4 sacc = {};
#pragma unroll
    for (int kcv = 0; kcv < 4; ++kcv) {
#pragma unroll
      for (int c2 = 0; c2 < 2; ++c2) {
        const int ct = kcv * 2 + c2;
        uint2 d2;
        d2.x = pk2(s2[ct][0], s2[ct][1]);
        d2.y = pk2(s2[ct][2], s2[ct][3]);
        *reinterpret_cast<uint2*>(&myP[lr * PS + c2 * 16 + qd * 4]) = d2;
      }
      const f16x8 pa = ldh8(&myP[lr * PS + qd * 8]);
#pragma unroll
      for (int nt = 0; nt < 4; ++nt) {
        const int rv = nt * 16 + lr;
        const f16x8 bv = ldh8(&shV[kcv * 2048 + rv * 32 + sw]);
        oacc[nt] = __builtin_amdgcn_mfma_f32_16x16x32_f16(bv, pa, oacc[nt], 0, 0, 0);
      }
      sacc = __builtin_amdgcn_mfma_f32_16x16x32_f16(ones, pa, sacc, 0, 0, 0);
    }
    lsum = lsum * alpha + sacc[0];
    __syncthreads();
  }

  // epilogue: O^T normalized by per-lane lsum, packed 8B stores
  const int b = bh >> 4, h = bh & 15;
  const float inv = 1.0f / lsum;
  const int q = q0 + w * 16 + lr;
#pragma unroll
  for (int nt = 0; nt < 4; ++nt) {
    unsigned short o[4];
#pragma unroll
    for (int r = 0; r < 4; ++r) o[r] = f2h(oacc[nt][r] * inv);
    const int col = h * 64 + nt * 16 + qd * 4;
    *reinterpret_cast<u16x4*>(&AOf[((size_t)b * Tn + q) * En + col]) =
        u16x4{o[0], o[1], o[2], o[3]};
  }
}

// Out-projection (r16 structure, measured-good: dbuf + XOR slot-swizzle,
// 2x-unrolled compile-time buf). OUT f32; A = AO fp16, B = wout fp16.
__global__ __launch_bounds__(256) void gemm_out(
    const unsigned short* __restrict__ A, const unsigned short* __restrict__ Bm,
    float* __restrict__ C, int M, int N, int K)
{
  // 2 x (A 4096 | B 4096 shorts) = 32768 B
  __shared__ unsigned short smem[2 * 8192];
  const int tid = threadIdx.x;
  const int w = tid >> 6, L = tid & 63, qd = L >> 4, lr = L & 15;
  const int m0 = blockIdx.y * 128;
  const int n0 = blockIdx.x * 128;
  const int wm = (w >> 1) * 64, wn = (w & 1) * 64;

  size_t aoffs[2], boffs[2];
  int lbase[2];
#pragma unroll
  for (int p = 0; p < 2; ++p) {
    const int c = p * 256 + tid;
    const int row = c >> 2, slot = c & 3;
    const int sg = slot ^ ((row >> 1) & 3);  // swizzled global 16B slot
    aoffs[p] = (size_t)(m0 + row) * K + sg * 8;
    boffs[p] = (size_t)(n0 + row) * K + sg * 8;
    lbase[p] = (p * 4 + w) * 512;
  }
  const int sw = (qd ^ ((lr >> 1) & 3)) * 8;

  f32x4 acc[4][4] = {};

  auto stage = [&](int k0s, int bufbase) {
#pragma unroll
    for (int p = 0; p < 2; ++p) {
      gld16(A + aoffs[p] + k0s, &smem[bufbase + lbase[p]]);
      gld16(Bm + boffs[p] + k0s, &smem[bufbase + 4096 + lbase[p]]);
    }
  };
  auto compute = [&](int cb) {
    f16x8 af[4], bf[4];
#pragma unroll
    for (int mt = 0; mt < 4; ++mt)
      af[mt] = ldh8(&smem[cb + (wm + mt * 16 + lr) * 32 + sw]);
#pragma unroll
    for (int nt = 0; nt < 4; ++nt)
      bf[nt] = ldh8(&smem[cb + 4096 + (wn + nt * 16 + lr) * 32 + sw]);
#pragma unroll
    for (int mt = 0; mt < 4; ++mt)
#pragma unroll
      for (int nt = 0; nt < 4; ++nt)
        acc[mt][nt] = __builtin_amdgcn_mfma_f32_16x16x32_f16(af[mt], bf[nt], acc[mt][nt], 0, 0, 0);
  };

  stage(0, 0);
  __syncthreads();

  for (int k0 = 0; k0 < K; k0 += 64) {
    if (k0 + 32 < K) stage(k0 + 32, 8192);
    compute(0);
    __syncthreads();
    if (k0 + 64 < K) stage(k0 + 64, 0);
    compute(8192);
    __syncthreads();
  }

#pragma unroll
  for (int mt = 0; mt < 4; ++mt)
#pragma unroll
    for (int nt = 0; nt < 4; ++nt)
#pragma unroll
      for (int r = 0; r < 4; ++r) {
        const int m = m0 + wm + mt * 16 + qd * 4 + r;
        const int n = n0 + wn + nt * 16 + lr;
        C[(size_t)m * N + n] = acc[mt][nt][r];
      }
}

extern "C" void kernel_launch(void* const* d_in, const int* in_sizes, int n_in,
                              void* d_out, int out_size, void* d_ws, size_t ws_size,
                              hipStream_t stream) {
  (void)in_sizes; (void)n_in; (void)out_size; (void)ws_size;
  const float* x = (const float*)d_in[0];      // [2,2048,1024] f32
  const float* wqkv = (const float*)d_in[1];   // [3072,1024]  f32
  const float* wout = (const float*)d_in[2];   // [1024,1024]  f32
  float* out = (float*)d_out;                  // [2,2048,1024] f32

  const size_t elems = (size_t)Bn * Hn * Tn * Dn;  // 4M elems (8 MiB fp16)
  unsigned short* Qf = (unsigned short*)d_ws;
  unsigned short* Kf = Qf + elems;
  unsigned short* Vf = Kf + elems;
  unsigned short* AOf = Vf + elems;
  unsigned short* wf = AOf + elems;                // fp16 w_qkv, 3M
  unsigned short* wof = wf + (size_t)3 * En * En;  // fp16 wout, 1M (40 MiB)

  // d_out (16 MiB) doubles as scratch for x hi/lo; overwritten by gemm_out.
  unsigned short* xh = (unsigned short*)d_out;
  unsigned short* xl = xh + elems;

  const int M = Bn * Tn;  // 4096
  dim3 blk(256);
  prep<<<dim3(8192), blk, 0, stream>>>(x, wqkv, wout, xh, xl, wf, wof);
  gemm_qkv<<<dim3(M / 128, 24), blk, 0, stream>>>(
      xh, xl, wf, Qf, Kf, Vf, M, En);
  attn_kernel<<<dim3(Bn * Hn, Tn / 64), blk, 0, stream>>>(Qf, Kf, Vf, AOf);
  gemm_out<<<dim3(En / 128, M / 128), blk, 0, stream>>>(
      AOf, wof, out, M, En, En);
}